// Round 4
// baseline (156.198 us; speedup 1.0000x reference)
//
#include <hip/hip_runtime.h>
#include <stdint.h>

// ---------------------------------------------------------------------------
// WeightGenerator_V4, round 7: g-paired k2 blocks (full-line output writes).
//   k1 (unchanged, known-good): gate -> gs; conv+dw3/dw5 -> f0; w_lin -> bf16.
//   k2: 256 blocks x 1024 threads (16 waves = 2 sub-groups of 8 waves).
//       sub s handles patch g = gp*2 + s; the two subs share barriers
//       (identical phase structure) and complete every 64-B output line
//       within the block -> no partial-line writeback amplification.
//       LDS 128 KB static: Ylds[2][32KB] + dynbuf[2][32KB] (scratch alias
//       Wd double-buffer). 1 block/CU, 256 blocks = exactly 1 round,
//       16 waves/CU.
//       Inner pipeline identical to r6: upfront y loads, j-paired full-K
//       gen MFMA (bias in C-in), 2-deep wlin register prefetch, swizzled
//       LDS (gen-write 4/bank, A2 8/bank, Bf 8/bank - optimal).
// ---------------------------------------------------------------------------

typedef __attribute__((ext_vector_type(8))) short short8;
typedef __attribute__((ext_vector_type(4))) float f32x4;

#define BN_EPS 1e-5f

__device__ __forceinline__ unsigned short f2bf(float f) {
  unsigned u = __float_as_uint(f);
  return (unsigned short)((u + 0x8000u) >> 16);
}
__device__ __forceinline__ unsigned pk2bf(float a, float b) {
  unsigned ua = __float_as_uint(a), ub = __float_as_uint(b);
  return ((ua + 0x8000u) >> 16) | ((ub + 0x8000u) & 0xFFFF0000u);
}

// =====================  k1: gate + conv/dw (role-split)  =====================
__global__ __launch_bounds__(256) void k1_merged(
    const float* __restrict__ x, const float* __restrict__ w_cr,
    const float* __restrict__ b_cr, const float* __restrict__ w_dw3,
    const float* __restrict__ b_dw3, const float* __restrict__ w_dw7,
    const float* __restrict__ b_dw7, const float* __restrict__ w_gate,
    const float* __restrict__ b_gate, const float* __restrict__ bn_gamma,
    const float* __restrict__ bn_beta, const float* __restrict__ bn_mean,
    const float* __restrict__ bn_var, const float* __restrict__ sr_scale,
    const float* __restrict__ sr_bias, const float* __restrict__ w_lin,
    short* __restrict__ wlin_bf, float* __restrict__ f0_out,
    float* __restrict__ gs_out)
{
  __shared__ __align__(16) float xcen[256];   // gate role
  __shared__ __align__(16) float xs[4][256];  // conv role
  __shared__ __align__(16) float xrs[256];    // conv role

  int blk = blockIdx.x;
  int t = threadIdx.x;

  if (blk < 512) {
    // ---------------- gate role: one pixel per block ----------------
    int b = blk >> 8, h = (blk >> 4) & 15, w = blk & 15;
    int pix = (b * 16 + h) * 16 + w;

    { int idx = blk * 256 + t; wlin_bf[idx] = (short)f2bf(w_lin[idx]); }

    xcen[t] = x[b * 65536 + t * 256 + h * 16 + w];
    __syncthreads();

    int wave = t >> 6, lane = t & 63;
    int oq = lane >> 2, ol = lane & 3;          // 16 outputs x 4 lanes
    const float4* wg4 = (const float4*)w_gate;
    const float4* xc4 = (const float4*)xcen;
    float ss = sr_scale[0], sb = sr_bias[0];

    #pragma unroll
    for (int pass = 0; pass < 2; ++pass) {
      int o = wave * 32 + pass * 16 + oq;       // [0,128)
      float acc = 0.f;
      #pragma unroll
      for (int k = 0; k < 16; ++k) {
        int j = k * 4 + ol;                     // float4 index over 256 ch
        float4 wv = wg4[o * 64 + j];            // quad-coalesced 64B lines
        float4 xv = xc4[j];                     // LDS broadcast
        acc += wv.x * xv.x + wv.y * xv.y + wv.z * xv.z + wv.w * xv.w;
      }
      acc += __shfl_xor(acc, 1);
      acc += __shfl_xor(acc, 2);
      float inv = bn_gamma[o] * rsqrtf(bn_var[o] + BN_EPS);
      float gg = (acc + b_gate[o] - bn_mean[o]) * inv + bn_beta[o];
      gg = fmaxf(gg, 0.f);
      gg = ss * gg * gg + sb;
      if (ol == 0) gs_out[pix * 128 + o] = gg;
    }
  } else {
    // ---------------- conv role: one (b, cr) channel-image ----------------
    int cb = blk - 512;
    int b = cb >> 6, cr = cb & 63;
    {
      int ch = t >> 6, off = (t & 63) * 4;
      float4 v = *(const float4*)(x + b * 65536 + (cr * 4 + ch) * 256 + off);
      *(float4*)&xs[ch][off] = v;
    }
    __syncthreads();
    int h = t >> 4, w = t & 15;
    float a = b_cr[cr];
    #pragma unroll
    for (int ii = 0; ii < 4; ++ii) {
      const float* wp = w_cr + (cr * 4 + ii) * 9;
      #pragma unroll
      for (int ky = 0; ky < 3; ++ky) {
        int gy = h + ky - 1;
        #pragma unroll
        for (int kx = 0; kx < 3; ++kx) {
          int gx = w + kx - 1;
          float v = (gy >= 0 && gy < 16 && gx >= 0 && gx < 16) ? xs[ii][gy * 16 + gx] : 0.f;
          a += wp[ky * 3 + kx] * v;
        }
      }
    }
    xrs[t] = a;
    __syncthreads();

    float f3 = b_dw3[cr];
    {
      const float* wp = w_dw3 + cr * 9;
      #pragma unroll
      for (int ky = 0; ky < 3; ++ky) {
        int gy = h + ky - 1;
        #pragma unroll
        for (int kx = 0; kx < 3; ++kx) {
          int gx = w + kx - 1;
          float v = (gy >= 0 && gy < 16 && gx >= 0 && gx < 16) ? xrs[gy * 16 + gx] : 0.f;
          f3 += wp[ky * 3 + kx] * v;
        }
      }
    }
    float f5 = b_dw7[cr];
    {
      const float* wp = w_dw7 + cr * 25;
      #pragma unroll
      for (int ky = 0; ky < 5; ++ky) {
        int gy = h + ky - 2;
        #pragma unroll
        for (int kx = 0; kx < 5; ++kx) {
          int gx = w + kx - 2;
          float v = (gy >= 0 && gy < 16 && gx >= 0 && gx < 16) ? xrs[gy * 16 + gx] : 0.f;
          f5 += wp[ky * 5 + kx] * v;
        }
      }
    }
    int pix = (b * 16 + h) * 16 + w;
    f0_out[pix * 128 + cr] = f3;
    f0_out[pix * 128 + 64 + cr] = f5;
  }
}

// =====================  k2: fused Wd-gen + dynamic conv (g-paired)  =========
// 256 blocks = 1 g-pair each. 1024 threads = 2 subs x 8 waves.
// LDS 128 KB: Ylds[2][32 KB] + dynbuf[2][32 KB]
//   (per-sub: stage scratch [64][65] f32 aliased with Wd dbuf [2][256e][32c]).
__global__ __launch_bounds__(1024, 4) void k2_fused(
    const float* __restrict__ y, const short* __restrict__ wlin_bf,
    const float* __restrict__ f0_in, const float* __restrict__ gs_in,
    const float* __restrict__ b_lin, float* __restrict__ out)
{
  __shared__ __align__(16) short Ylds[2][16384];  // per-sub [pix][32 gran of 8c]
  __shared__ __align__(16) char dynbuf[2][32768];

  int tid = threadIdx.x;
  int sub = tid >> 9;                           // patch parity within pair
  int st = tid & 511;                           // index within sub-group
  int phys = blockIdx.x;
  int pblk = (phys & 7) * 32 + (phys >> 3);     // XCD-contiguous pair id
  int b = pblk >> 7, f = (pblk >> 3) & 15, gp = pblk & 7;
  int g = gp * 2 + sub;
  int blk = (b * 16 + f) * 16 + g;              // patch id for f0/gs

  int wave = st >> 6, lane = tid & 63;
  int quad = lane >> 4, l16 = lane & 15;
  int geff = l16 & 7, jsel = l16 >> 3;

  float* scratch = (float*)dynbuf[sub];         // [64 c][65] f32 (staging)
  short* wdbuf = (short*)dynbuf[sub];           // [2][256 e][32 c] bf16
  short* yl = Ylds[sub];

  const float* yb = y + b * 4194304 + (f * 8) * 128 + g * 8;

  // ---- issue ALL y loads upfront: 8 float4/thread, one exposed latency ----
  int c32 = st >> 4, pf = st & 15;              // 32 c x 16 pixel-float4
  float4 yv[4][2];
  #pragma unroll
  for (int sch = 0; sch < 4; ++sch)
    #pragma unroll
    for (int it = 0; it < 2; ++it)
      yv[sch][it] = *(const float4*)(yb + (sch * 64 + it * 32 + c32) * 16384 + (pf >> 1) * 128 + (pf & 1) * 4);

  // ---- issue wlin prefetch for chunks 0,1 (slot = chunk&1) ----
  short8 aw[2][2][2];                           // [slot][jj][hh]
  #pragma unroll
  for (int s = 0; s < 2; ++s)
    #pragma unroll
    for (int jj = 0; jj < 2; ++jj) {
      int jA = (wave * 2 + jj) * 2 + (quad >> 1);
      #pragma unroll
      for (int hh = 0; hh < 2; ++hh) {
        int c0 = s * 32 + hh * 16;
        aw[s][jj][hh] = *(const short8*)(wlin_bf + (jA * 256 + c0 + l16) * 16 + (quad & 1) * 8);
      }
    }

  // ---- issue f0/gs loads (packed into bx after staging) ----
  bool bval = (jsel == (quad >> 1));
  const float* f0p = f0_in + blk * 128 + geff * 16 + (quad & 1) * 8;
  const float* gsp = gs_in + blk * 128 + geff * 16 + (quad & 1) * 8;
  float4 f0a = *(const float4*)f0p, f0b = *(const float4*)(f0p + 4);
  float4 gsa = *(const float4*)gsp, gsb = *(const float4*)(gsp + 4);

  // ---- stage Y: 4 pure-LDS rounds of 64 channels ----
  #pragma unroll
  for (int sch = 0; sch < 4; ++sch) {
    #pragma unroll
    for (int it = 0; it < 2; ++it)
      *(float4*)&scratch[(it * 32 + c32) * 65 + pf * 4] = yv[sch][it];
    __syncthreads();
    {
      int pix = st & 63, cg = st >> 6;          // 64 pix x 8 c-groups of 8
      float s0 = scratch[(cg * 8 + 0) * 65 + pix];
      float s1 = scratch[(cg * 8 + 1) * 65 + pix];
      float s2 = scratch[(cg * 8 + 2) * 65 + pix];
      float s3 = scratch[(cg * 8 + 3) * 65 + pix];
      float s4 = scratch[(cg * 8 + 4) * 65 + pix];
      float s5 = scratch[(cg * 8 + 5) * 65 + pix];
      float s6 = scratch[(cg * 8 + 6) * 65 + pix];
      float s7 = scratch[(cg * 8 + 7) * 65 + pix];
      uint4 pk;
      pk.x = pk2bf(s0, s1); pk.y = pk2bf(s2, s3);
      pk.z = pk2bf(s4, s5); pk.w = pk2bf(s6, s7);
      int chunk = sch * 8 + cg;                 // 8-ch group id [0,32)
      int physc = chunk ^ (pix & 15);           // read-optimal swizzle
      *(uint4*)&yl[pix * 256 + physc * 8] = pk;
    }
    __syncthreads();
  }

  // ---- xc fragment: B[k][n=jsel*8+geff] = xc[geff][k%16] iff k>>4==jsel ----
  short8 bx = {0, 0, 0, 0, 0, 0, 0, 0};
  if (bval) {
    bx[0] = (short)f2bf(f0a.x * gsa.x); bx[1] = (short)f2bf(f0a.y * gsa.y);
    bx[2] = (short)f2bf(f0a.z * gsa.z); bx[3] = (short)f2bf(f0a.w * gsa.w);
    bx[4] = (short)f2bf(f0b.x * gsb.x); bx[5] = (short)f2bf(f0b.y * gsb.y);
    bx[6] = (short)f2bf(f0b.z * gsb.z); bx[7] = (short)f2bf(f0b.w * gsb.w);
  }

  f32x4 acc[2][4];
  #pragma unroll
  for (int et = 0; et < 2; ++et)
    #pragma unroll
    for (int nt = 0; nt < 4; ++nt)
      acc[et][nt] = {0.f, 0.f, 0.f, 0.f};

  // ---- j-paired generator: 256e x 32c chunk, 4 MFMA/wave, bias in C-in ----
  auto gen_chunk = [&](int cc, int buf, int slot) {
    short* dst = wdbuf + buf * 8192;
    #pragma unroll
    for (int jj = 0; jj < 2; ++jj) {
      int jp = wave * 2 + jj;
      int jD = jp * 2 + jsel;
      #pragma unroll
      for (int hh = 0; hh < 2; ++hh) {
        int c0 = cc * 32 + hh * 16;
        float4 bl = *(const float4*)(b_lin + jD * 256 + c0 + quad * 4);
        f32x4 cin = {bl.x, bl.y, bl.z, bl.w};
        f32x4 d = __builtin_amdgcn_mfma_f32_16x16x32_bf16(aw[slot][jj][hh], bx, cin, 0, 0, 0);
        int e = geff * 32 + jD;
        uint2 pk;
        pk.x = pk2bf(d[0], d[1]);
        pk.y = pk2bf(d[2], d[3]);
        int q16 = hh * 2 + (quad >> 1);
        int sw = q16 ^ ((e >> 1) & 3) ^ ((e >> 5) & 3);
        *(uint2*)&dst[e * 32 + sw * 8 + (quad & 1) * 4] = pk;
      }
    }
  };

  gen_chunk(0, 0, 0);
  __syncthreads();

  // ---- K-loop: 8 chunks; gen(cc+1) + wlin-prefetch(cc+2) overlap use(cc) ----
  #pragma unroll
  for (int cc = 0; cc < 8; ++cc) {
    if (cc < 6) {                               // prefetch wlin for chunk cc+2
      #pragma unroll
      for (int jj = 0; jj < 2; ++jj) {
        int jA = (wave * 2 + jj) * 2 + (quad >> 1);
        #pragma unroll
        for (int hh = 0; hh < 2; ++hh) {
          int c0 = (cc + 2) * 32 + hh * 16;
          aw[cc & 1][jj][hh] = *(const short8*)(wlin_bf + (jA * 256 + c0 + l16) * 16 + (quad & 1) * 8);
        }
      }
    }
    if (cc < 7) gen_chunk(cc + 1, (cc + 1) & 1, (cc + 1) & 1);

    const short* src = wdbuf + (cc & 1) * 8192;
    short8 A2[2], Bf[4];
    #pragma unroll
    for (int et = 0; et < 2; ++et) {
      int e = wave * 32 + et * 16 + l16;
      int sw = quad ^ ((e >> 1) & 3) ^ ((e >> 5) & 3);
      A2[et] = *(const short8*)&src[e * 32 + sw * 8];
    }
    int chunkY = cc * 4 + quad;
    #pragma unroll
    for (int nt = 0; nt < 4; ++nt) {
      int physc = chunkY ^ l16;                 // nn&15 == l16
      Bf[nt] = *(const short8*)&yl[(nt * 16 + l16) * 256 + physc * 8];
    }
    #pragma unroll
    for (int et = 0; et < 2; ++et)
      #pragma unroll
      for (int nt = 0; nt < 4; ++nt)
        acc[et][nt] = __builtin_amdgcn_mfma_f32_16x16x32_bf16(A2[et], Bf[nt], acc[et][nt], 0, 0, 0);
    if (cc < 7) __syncthreads();
  }

  // ---- epilogue: D row=quad*4+r -> e, col=l16 -> pix ----
  // sub 0/1 write the low/high 32B halves of every 64B line concurrently.
  float* ob = out + b * 4194304 + (f * 8) * 128 + g * 8;
  #pragma unroll
  for (int et = 0; et < 2; ++et) {
    int e0 = wave * 32 + et * 16 + quad * 4;
    #pragma unroll
    for (int nt = 0; nt < 4; ++nt) {
      int pix = nt * 16 + l16;
      float* oa = ob + (pix >> 3) * 128 + (pix & 7);
      #pragma unroll
      for (int r = 0; r < 4; ++r)
        oa[(e0 + r) * 16384] = acc[et][nt][r];
    }
  }
}

// ============================  launcher  ============================
extern "C" void kernel_launch(void* const* d_in, const int* in_sizes, int n_in,
                              void* d_out, int out_size, void* d_ws, size_t ws_size,
                              hipStream_t stream) {
  const float* x        = (const float*)d_in[0];
  const float* y        = (const float*)d_in[1];
  const float* w_cr     = (const float*)d_in[2];
  const float* b_cr     = (const float*)d_in[3];
  const float* w_dw3    = (const float*)d_in[4];
  const float* b_dw3    = (const float*)d_in[5];
  const float* w_dw7    = (const float*)d_in[6];
  const float* b_dw7    = (const float*)d_in[7];
  const float* w_gate   = (const float*)d_in[8];
  const float* b_gate   = (const float*)d_in[9];
  const float* bn_gamma = (const float*)d_in[10];
  const float* bn_beta  = (const float*)d_in[11];
  const float* bn_mean  = (const float*)d_in[12];
  const float* bn_var   = (const float*)d_in[13];
  const float* sr_scale = (const float*)d_in[14];
  const float* sr_bias  = (const float*)d_in[15];
  const float* w_lin    = (const float*)d_in[16];
  const float* b_lin    = (const float*)d_in[17];
  float* out = (float*)d_out;

  // ws layout: f0 256KB | gs 256KB | wlin_bf 256KB
  float* f0      = (float*)d_ws;
  float* gs      = (float*)((char*)d_ws + 262144);
  short* wlin_bf = (short*)((char*)d_ws + 524288);

  hipLaunchKernelGGL(k1_merged, dim3(640), dim3(256), 0, stream,
                     x, w_cr, b_cr, w_dw3, b_dw3, w_dw7, b_dw7, w_gate, b_gate,
                     bn_gamma, bn_beta, bn_mean, bn_var, sr_scale, sr_bias,
                     w_lin, wlin_bf, f0, gs);
  hipLaunchKernelGGL(k2_fused, dim3(256), dim3(1024), 0, stream,
                     y, wlin_bf, f0, gs, b_lin, out);
}